// Round 5
// baseline (1857.672 us; speedup 1.0000x reference)
//
#include <hip/hip_runtime.h>
#include <math.h>

// ---------------- problem constants ----------------
#define NTREES 128
#define NPT 127
#define NNODES (NTREES*NPT)      // 16256
#define EUP (NTREES*(NPT-1))     // 16128
#define HDIM 450
#define HP 512
#define LMAX 8192
#define NLVL 12

typedef unsigned short u16;
typedef __attribute__((ext_vector_type(8))) short bf16x8;
typedef __attribute__((ext_vector_type(4))) float f32x4;

__device__ __forceinline__ float sigmoidf_(float x) { return 1.f / (1.f + expf(-x)); }
__device__ __forceinline__ u16 f2b(float x) {
  unsigned u = __float_as_uint(x);
  return (u16)((u + 0x7FFFu + ((u >> 16) & 1u)) >> 16);
}
__device__ __forceinline__ float b2f(u16 h) { return __uint_as_float(((unsigned)h) << 16); }
__device__ __forceinline__ bf16x8 sub8(bf16x8 a, bf16x8 b) {
  bf16x8 r;
#pragma unroll
  for (int i = 0; i < 8; ++i) r[i] = (short)f2b(b2f((u16)a[i]) - b2f((u16)b[i]));
  return r;
}

// B tile LDS: [64 rows][64 bf16], 8 slots of 16B, XOR-swizzled by row&7
__device__ __forceinline__ u16* ldsp(u16* base, int row, int slot) {
  return base + row * 64 + ((slot ^ (row & 7)) << 3);
}
// A tile LDS: [32 rows][512 bf16], 64 slots of 16B, low-3 slot bits XOR row&7
__device__ __forceinline__ int physA(int row, int lslot) {
  return row * 512 + (((lslot & ~7) | ((lslot & 7) ^ (row & 7))) << 3);
}
#define MFMA(a, b, c) __builtin_amdgcn_mfma_f32_16x16x32_bf16(a, b, c, 0, 0, 0)

// ============== zero-fill ==============
__global__ void zero_ws(float4* __restrict__ p, int n4) {
  int i = blockIdx.x * 256 + threadIdx.x;
  int stride = gridDim.x * 256;
  for (; i < n4; i += stride) p[i] = make_float4(0.f, 0.f, 0.f, 0.f);
}

// ============== prep: bf16 TRANSPOSED zero-padded weights ==============
__global__ void prep_pad(const float* __restrict__ Wz, const float* __restrict__ Wh,
                         const float* __restrict__ Wr, const float* __restrict__ Ur,
                         const float* __restrict__ Wg,
                         const float* __restrict__ bz, const float* __restrict__ bh,
                         const float* __restrict__ bur, const float* __restrict__ bg,
                         u16* __restrict__ WpreT, u16* __restrict__ WzbT,
                         u16* __restrict__ WhbT, u16* __restrict__ UrT,
                         u16* __restrict__ WgT, float* __restrict__ biasp) {
  int idx = blockIdx.x * 256 + threadIdx.x;
  if (idx < 1536 * 512) {                         // WpreT[n][k]
    int n = idx >> 9, k = idx & 511;
    int sel = n >> 9, j = n & 511;
    float v = 0.f;
    if (k < HDIM && j < HDIM) {
      const float* W = (sel == 0) ? Wz : (sel == 1) ? Wh : Wr;
      v = W[k * HDIM + j];
    }
    WpreT[idx] = f2b(v);
    return;
  }
  idx -= 1536 * 512;
  if (idx < 3 * 262144) {                         // WzbT, WhbT, UrT
    int which = idx >> 18; int r = idx & 262143;
    int n = r >> 9, k = r & 511;
    float v = 0.f;
    if (k < HDIM && n < HDIM)
      v = (which == 0) ? Wz[(HDIM + k) * HDIM + n]
        : (which == 1) ? Wh[(HDIM + k) * HDIM + n]
                       : Ur[k * HDIM + n];
    ((which == 0) ? WzbT : (which == 1) ? WhbT : UrT)[r] = f2b(v);
    return;
  }
  idx -= 3 * 262144;
  if (idx < 512 * 1024) {                         // WgT[n][k]
    int n = idx >> 10, k = idx & 1023;
    float v = 0.f;
    if (n < HDIM) {
      if (k < HDIM) v = Wg[k * HDIM + n];
      else if (k >= HP && (k - HP) < HDIM) v = Wg[(HDIM + k - HP) * HDIM + n];
    }
    WgT[idx] = f2b(v);
    return;
  }
  idx -= 512 * 1024;
  if (idx < 4 * HP) {
    int which = idx >> 9, j = idx & 511;
    float v = 0.f;
    if (j < HDIM)
      v = ((which == 0) ? bz : (which == 1) ? bh : (which == 2) ? bur : bg)[j];
    biasp[idx] = v;
  }
}

// ============== embedding gather -> bf16 x_p[NNODES][512] ==============
__global__ void gather_embed(const int* __restrict__ wid, const float* __restrict__ emb,
                             u16* __restrict__ xp) {
  int gid = blockIdx.x * 256 + threadIdx.x;
  if (gid >= NNODES * 64) return;
  int row = gid >> 6, g = gid & 63;
  int j0 = g * 8;
  const float* er = emb + (size_t)wid[row] * HDIM;
  float f[8] = {0.f, 0.f, 0.f, 0.f, 0.f, 0.f, 0.f, 0.f};
  if (j0 <= 440) {
#pragma unroll
    for (int q = 0; q < 4; ++q) {
      float2 p = *(const float2*)(er + j0 + q * 2);
      f[q * 2] = p.x; f[q * 2 + 1] = p.y;
    }
  } else if (j0 == 448) {
    f[0] = er[448]; f[1] = er[449];
  }
  bf16x8 v;
#pragma unroll
  for (int q = 0; q < 8; ++q) v[q] = (short)f2b(f[q]);
  *(bf16x8*)(xp + (size_t)row * HP + j0) = v;
}

// ============== MFMA GEMM: Xpre = x @ Wpre -> bf16 Xzh, Xr (XCD-swizzled) ==============
__global__ __launch_bounds__(256, 4) void mfma_pre(
    const u16* __restrict__ xp, const u16* __restrict__ WpreT,
    u16* __restrict__ Xzh, u16* __restrict__ Xr) {
  __shared__ u16 Al[64 * 64], Bl[64 * 64];
  int bid = blockIdx.x;                // grid = 256*24
  int xcd = bid & 7, q0 = bid >> 3;
  int nt = q0 % 24;
  int mt = (q0 / 24) * 8 + xcd;
  if (mt >= NNODES / 64) return;
  int n0 = nt * 64, m0 = mt * 64;
  int tid = threadIdx.x;
  int l = tid & 63, w = tid >> 6, wr = w >> 1, wc = w & 1, lr = l & 15, lq = l >> 4;
  int sr = tid >> 2, skc = tid & 3;
  const u16* abase = xp + (size_t)(m0 + sr) * HP + skc * 16;
  const u16* bbase = WpreT + (size_t)(n0 + sr) * HP + skc * 16;
  f32x4 acc[2][2] = {};
  for (int kt = 0; kt < HP; kt += 64) {
    *(bf16x8*)ldsp(Al, sr, 2 * skc) = ((const bf16x8*)(abase + kt))[0];
    *(bf16x8*)ldsp(Al, sr, 2 * skc + 1) = ((const bf16x8*)(abase + kt))[1];
    *(bf16x8*)ldsp(Bl, sr, 2 * skc) = ((const bf16x8*)(bbase + kt))[0];
    *(bf16x8*)ldsp(Bl, sr, 2 * skc + 1) = ((const bf16x8*)(bbase + kt))[1];
    __syncthreads();
#pragma unroll
    for (int kk = 0; kk < 64; kk += 32) {
      int slot = (kk >> 3) + lq;
      bf16x8 fa0 = *(bf16x8*)ldsp(Al, wr * 32 + lr, slot);
      bf16x8 fa1 = *(bf16x8*)ldsp(Al, wr * 32 + 16 + lr, slot);
      bf16x8 fb0 = *(bf16x8*)ldsp(Bl, wc * 32 + lr, slot);
      bf16x8 fb1 = *(bf16x8*)ldsp(Bl, wc * 32 + 16 + lr, slot);
      acc[0][0] = MFMA(fa0, fb0, acc[0][0]); acc[0][1] = MFMA(fa0, fb1, acc[0][1]);
      acc[1][0] = MFMA(fa1, fb0, acc[1][0]); acc[1][1] = MFMA(fa1, fb1, acc[1][1]);
    }
    __syncthreads();
  }
#pragma unroll
  for (int fi = 0; fi < 2; ++fi)
#pragma unroll
    for (int fj = 0; fj < 2; ++fj) {
      int colg = n0 + wc * 32 + fj * 16 + lr;
#pragma unroll
      for (int reg = 0; reg < 4; ++reg) {
        int row = m0 + wr * 32 + fi * 16 + lq * 4 + reg;
        u16 o = f2b(acc[fi][fj][reg]);
        if (colg < 1024) Xzh[(size_t)row * 1024 + colg] = o;
        else Xr[(size_t)row * HP + (colg - 1024)] = o;
      }
    }
}

// ============== fused per-level kernel ==============
// mode 0: up (GEMM1 + GEMM2); mode 1: down; mode 2: level-0 (leaf elementwise + GEMM2)
// block = 32 edges x full N=512; A tiles live in LDS once.
__global__ __launch_bounds__(256, 2) void fused_level(
    int mode, const int* __restrict__ schedrow, const int* __restrict__ src,
    const int* __restrict__ dst,
    u16* __restrict__ node_m, u16* __restrict__ node_rm,
    u16* __restrict__ mup, u16* __restrict__ rmup,
    const u16* __restrict__ Xzh, const u16* __restrict__ Xr,
    const u16* __restrict__ WzbT, const u16* __restrict__ WhbT,
    const u16* __restrict__ UrT, const float* __restrict__ biasp) {
  __shared__ __align__(16) u16 As[32 * 512];   // s -> m_new
  __shared__ __align__(16) u16 Aa[32 * 512];   // arm -> rm
  __shared__ __align__(16) u16 Bz[64 * 64];
  __shared__ __align__(16) u16 Bt[64 * 64];
  int tid = threadIdx.x;
  int m0 = blockIdx.x * 32;

  // ---------- stage A (32 rows x 512) ----------
  int srow = tid >> 3, sj = tid & 7;
  int e_st = schedrow[m0 + srow];
  int se_st = src[e_st];
  if (mode == 0) {
    const u16* pm = node_m + (size_t)se_st * HP;
    const u16* pr = node_rm + (size_t)se_st * HP;
#pragma unroll
    for (int q = 0; q < 8; ++q) {
      int ls = (sj ^ (srow & 7)) + q * 8;
      int col = ls * 8;
      *(bf16x8*)&As[physA(srow, ls)] = *(const bf16x8*)(pm + col);
      *(bf16x8*)&Aa[physA(srow, ls)] = *(const bf16x8*)(pr + col);
    }
  } else if (mode == 1) {
    int eu = e_st - EUP;
    const u16* pm = node_m + (size_t)se_st * HP;
    const u16* pu = mup + (size_t)eu * HP;
    const u16* pr = node_rm + (size_t)se_st * HP;
    const u16* pv = rmup + (size_t)eu * HP;
#pragma unroll
    for (int q = 0; q < 8; ++q) {
      int ls = (sj ^ (srow & 7)) + q * 8;
      int col = ls * 8;
      *(bf16x8*)&As[physA(srow, ls)] =
          sub8(*(const bf16x8*)(pm + col), *(const bf16x8*)(pu + col));
      *(bf16x8*)&Aa[physA(srow, ls)] =
          sub8(*(const bf16x8*)(pr + col), *(const bf16x8*)(pv + col));
    }
  } else {  // mode 2: leaf m_new = sig(Xz+bz)*tanh(Xh+bh); persist mup
    const u16* xzp = Xzh + (size_t)se_st * 1024;
    u16* mo = mup + (size_t)e_st * HP;
#pragma unroll
    for (int q = 0; q < 8; ++q) {
      int ls = (sj ^ (srow & 7)) + q * 8;
      int col = ls * 8;
      bf16x8 vz = *(const bf16x8*)(xzp + col);
      bf16x8 vh = *(const bf16x8*)(xzp + 512 + col);
      bf16x8 o;
#pragma unroll
      for (int k = 0; k < 8; ++k) {
        float z = sigmoidf_(b2f((u16)vz[k]) + biasp[col + k]);
        float t = tanhf(b2f((u16)vh[k]) + biasp[512 + col + k]);
        o[k] = (short)f2b(z * t);
      }
      *(bf16x8*)&As[physA(srow, ls)] = o;
      *(bf16x8*)(mo + col) = o;
    }
  }
  __syncthreads();

  int l = tid & 63, w = tid >> 6;
  int wr = w >> 1, wc = w & 1, lr = l & 15, lq = l >> 4;
  int bsr = tid >> 2, bskc = tid & 3;
  int rowb = wr * 16 + lq * 4;
  int e_r[4], se_r[4], de_r[4];
#pragma unroll
  for (int i = 0; i < 4; ++i) {
    e_r[i] = schedrow[m0 + rowb + i];
    se_r[i] = src[e_r[i]];
    de_r[i] = dst[e_r[i]];
  }

  float mn[8][8];   // [n0-tile][fj*4+reg] — all indices compile-time (full unroll)
  if (mode < 2) {
    // ================= GEMM1 (dual Z/T) =================
#pragma unroll
    for (int t8 = 0; t8 < 8; ++t8) {
      f32x4 aZ[2] = {}, aT[2] = {};
      for (int kt8 = 0; kt8 < 8; ++kt8) {
        const u16* bz = WzbT + (size_t)(t8 * 64 + bsr) * HP + kt8 * 64 + bskc * 16;
        const u16* bt = WhbT + (size_t)(t8 * 64 + bsr) * HP + kt8 * 64 + bskc * 16;
        *(bf16x8*)ldsp(Bz, bsr, 2 * bskc) = ((const bf16x8*)bz)[0];
        *(bf16x8*)ldsp(Bz, bsr, 2 * bskc + 1) = ((const bf16x8*)bz)[1];
        *(bf16x8*)ldsp(Bt, bsr, 2 * bskc) = ((const bf16x8*)bt)[0];
        *(bf16x8*)ldsp(Bt, bsr, 2 * bskc + 1) = ((const bf16x8*)bt)[1];
        __syncthreads();
#pragma unroll
        for (int kk = 0; kk < 2; ++kk) {
          int arow = wr * 16 + lr;
          bf16x8 a0 = *(const bf16x8*)&As[physA(arow, kt8 * 8 + kk * 4 + lq)];
          bf16x8 c0 = *(const bf16x8*)&Aa[physA(arow, kt8 * 8 + kk * 4 + lq)];
          bf16x8 z0 = *(const bf16x8*)ldsp(Bz, wc * 32 + lr, kk * 4 + lq);
          bf16x8 z1 = *(const bf16x8*)ldsp(Bz, wc * 32 + 16 + lr, kk * 4 + lq);
          bf16x8 t0 = *(const bf16x8*)ldsp(Bt, wc * 32 + lr, kk * 4 + lq);
          bf16x8 t1 = *(const bf16x8*)ldsp(Bt, wc * 32 + 16 + lr, kk * 4 + lq);
          aZ[0] = MFMA(a0, z0, aZ[0]); aZ[1] = MFMA(a0, z1, aZ[1]);
          aT[0] = MFMA(c0, t0, aT[0]); aT[1] = MFMA(c0, t1, aT[1]);
        }
        __syncthreads();
      }
#pragma unroll
      for (int fj = 0; fj < 2; ++fj)
#pragma unroll
        for (int reg = 0; reg < 4; ++reg) {
          int row = rowb + reg;
          int lcol = t8 * 64 + wc * 32 + fj * 16 + lr;
          float s = b2f(As[physA(row, lcol >> 3) + (lcol & 7)]);
          float xz = b2f(Xzh[(size_t)se_r[reg] * 1024 + lcol]);
          float xh = b2f(Xzh[(size_t)se_r[reg] * 1024 + 512 + lcol]);
          float z = sigmoidf_(aZ[fj][reg] + xz + biasp[lcol]);
          float t = tanhf(aT[fj][reg] + xh + biasp[512 + lcol]);
          mn[t8][fj * 4 + reg] = (1.f - z) * s + z * t;
        }
    }
    __syncthreads();   // all GEMM1 reads of As/Aa complete
    // scatter m_new into As (overwrites s)
#pragma unroll
    for (int t8 = 0; t8 < 8; ++t8)
#pragma unroll
      for (int fj = 0; fj < 2; ++fj)
#pragma unroll
        for (int reg = 0; reg < 4; ++reg) {
          int row = rowb + reg;
          int lcol = t8 * 64 + wc * 32 + fj * 16 + lr;
          As[physA(row, lcol >> 3) + (lcol & 7)] = f2b(mn[t8][fj * 4 + reg]);
        }
    __syncthreads();
    if (mode == 0) {   // persist mup (coalesced from LDS)
      u16* mo = mup + (size_t)e_st * HP;
#pragma unroll
      for (int q = 0; q < 8; ++q) {
        int ls = (sj ^ (srow & 7)) + q * 8;
        *(bf16x8*)(mo + ls * 8) = *(const bf16x8*)&As[physA(srow, ls)];
      }
    }
  }

  // ================= GEMM2: r = sig(Xr[de] + m_new@Ur + bur); rm -> Aa =================
#pragma unroll
  for (int t8 = 0; t8 < 8; ++t8) {
    f32x4 aR[2] = {};
    for (int kt8 = 0; kt8 < 8; ++kt8) {
      const u16* bu = UrT + (size_t)(t8 * 64 + bsr) * HP + kt8 * 64 + bskc * 16;
      *(bf16x8*)ldsp(Bz, bsr, 2 * bskc) = ((const bf16x8*)bu)[0];
      *(bf16x8*)ldsp(Bz, bsr, 2 * bskc + 1) = ((const bf16x8*)bu)[1];
      __syncthreads();
#pragma unroll
      for (int kk = 0; kk < 2; ++kk) {
        int arow = wr * 16 + lr;
        bf16x8 a0 = *(const bf16x8*)&As[physA(arow, kt8 * 8 + kk * 4 + lq)];
        bf16x8 b0 = *(const bf16x8*)ldsp(Bz, wc * 32 + lr, kk * 4 + lq);
        bf16x8 b1 = *(const bf16x8*)ldsp(Bz, wc * 32 + 16 + lr, kk * 4 + lq);
        aR[0] = MFMA(a0, b0, aR[0]); aR[1] = MFMA(a0, b1, aR[1]);
      }
      __syncthreads();
    }
#pragma unroll
    for (int fj = 0; fj < 2; ++fj)
#pragma unroll
      for (int reg = 0; reg < 4; ++reg) {
        int row = rowb + reg;
        int lcol = t8 * 64 + wc * 32 + fj * 16 + lr;
        float r = sigmoidf_(aR[fj][reg] + b2f(Xr[(size_t)de_r[reg] * HP + lcol]) +
                            biasp[1024 + lcol]);
        float mv = b2f(As[physA(row, lcol >> 3) + (lcol & 7)]);
        Aa[physA(row, lcol >> 3) + (lcol & 7)] = f2b(r * mv);
      }
  }
  __syncthreads();

  // ================= final linear phase =================
  if (mode == 1) {
    // down: node accumulators += (dst unique within level)
    int de = dst[e_st];
    u16* nm = node_m + (size_t)de * HP;
    u16* nr = node_rm + (size_t)de * HP;
#pragma unroll
    for (int q = 0; q < 8; ++q) {
      int ls = (sj ^ (srow & 7)) + q * 8;
      int col = ls * 8;
      bf16x8 mv = *(const bf16x8*)&As[physA(srow, ls)];
      bf16x8 rv = *(const bf16x8*)&Aa[physA(srow, ls)];
      bf16x8 om = *(const bf16x8*)(nm + col);
      bf16x8 orr = *(const bf16x8*)(nr + col);
      bf16x8 sm, sr2;
#pragma unroll
      for (int k = 0; k < 8; ++k) {
        sm[k] = (short)f2b(b2f((u16)om[k]) + b2f((u16)mv[k]));
        sr2[k] = (short)f2b(b2f((u16)orr[k]) + b2f((u16)rv[k]));
      }
      *(bf16x8*)(nm + col) = sm;
      *(bf16x8*)(nr + col) = sr2;
    }
  } else {
    // up: persist rmup; pair-sum (siblings adjacent) -> node_m/node_rm store
    u16* ro = rmup + (size_t)e_st * HP;
#pragma unroll
    for (int q = 0; q < 8; ++q) {
      int ls = (sj ^ (srow & 7)) + q * 8;
      *(bf16x8*)(ro + ls * 8) = *(const bf16x8*)&Aa[physA(srow, ls)];
    }
    int p = tid >> 4, l16 = tid & 15;
    int dep = dst[schedrow[m0 + 2 * p]];
    u16* nm = node_m + (size_t)dep * HP;
    u16* nr = node_rm + (size_t)dep * HP;
#pragma unroll
    for (int q = 0; q < 4; ++q) {
      int ls = l16 + q * 16;
      int col = ls * 8;
      bf16x8 a0 = *(const bf16x8*)&As[physA(2 * p, ls)];
      bf16x8 a1 = *(const bf16x8*)&As[physA(2 * p + 1, ls)];
      bf16x8 r0 = *(const bf16x8*)&Aa[physA(2 * p, ls)];
      bf16x8 r1 = *(const bf16x8*)&Aa[physA(2 * p + 1, ls)];
      bf16x8 sm, sr2;
#pragma unroll
      for (int k = 0; k < 8; ++k) {
        sm[k] = (short)f2b(b2f((u16)a0[k]) + b2f((u16)a1[k]));
        sr2[k] = (short)f2b(b2f((u16)r0[k]) + b2f((u16)r1[k]));
      }
      *(bf16x8*)(nm + col) = sm;
      *(bf16x8*)(nr + col) = sr2;
    }
  }
}

// ============== final GEMM: h = relu([x, node_m] @ Wg + bg) (XCD-swizzled) ==============
__global__ __launch_bounds__(256, 4) void mfma_final(
    const u16* __restrict__ xp, const u16* __restrict__ node_m,
    const u16* __restrict__ WgT, const float* __restrict__ biasp,
    float* __restrict__ out) {
  __shared__ u16 Al[64 * 64], Bl[64 * 64];
  int bid = blockIdx.x;                // grid = 256*8
  int xcd = bid & 7, q0 = bid >> 3;
  int nt = q0 % 8;
  int mt = (q0 / 8) * 8 + xcd;
  if (mt >= NNODES / 64) return;
  int n0 = nt * 64, m0 = mt * 64;
  int tid = threadIdx.x;
  int l = tid & 63, w = tid >> 6, wr = w >> 1, wc = w & 1, lr = l & 15, lq = l >> 4;
  int sr = tid >> 2, skc = tid & 3;
  const u16* axb = xp + (size_t)(m0 + sr) * HP + skc * 16;
  const u16* anb = node_m + (size_t)(m0 + sr) * HP + skc * 16;
  const u16* bb = WgT + (size_t)(n0 + sr) * 1024 + skc * 16;
  f32x4 acc[2][2] = {};
  for (int kt = 0; kt < 1024; kt += 64) {
    const u16* ap = (kt < HP) ? (axb + kt) : (anb + (kt - HP));
    *(bf16x8*)ldsp(Al, sr, 2 * skc) = ((const bf16x8*)ap)[0];
    *(bf16x8*)ldsp(Al, sr, 2 * skc + 1) = ((const bf16x8*)ap)[1];
    *(bf16x8*)ldsp(Bl, sr, 2 * skc) = ((const bf16x8*)(bb + kt))[0];
    *(bf16x8*)ldsp(Bl, sr, 2 * skc + 1) = ((const bf16x8*)(bb + kt))[1];
    __syncthreads();
#pragma unroll
    for (int kk = 0; kk < 64; kk += 32) {
      int slot = (kk >> 3) + lq;
      bf16x8 fa0 = *(bf16x8*)ldsp(Al, wr * 32 + lr, slot);
      bf16x8 fa1 = *(bf16x8*)ldsp(Al, wr * 32 + 16 + lr, slot);
      bf16x8 fb0 = *(bf16x8*)ldsp(Bl, wc * 32 + lr, slot);
      bf16x8 fb1 = *(bf16x8*)ldsp(Bl, wc * 32 + 16 + lr, slot);
      acc[0][0] = MFMA(fa0, fb0, acc[0][0]); acc[0][1] = MFMA(fa0, fb1, acc[0][1]);
      acc[1][0] = MFMA(fa1, fb0, acc[1][0]); acc[1][1] = MFMA(fa1, fb1, acc[1][1]);
    }
    __syncthreads();
  }
#pragma unroll
  for (int fi = 0; fi < 2; ++fi)
#pragma unroll
    for (int fj = 0; fj < 2; ++fj) {
      int colg = n0 + wc * 32 + fj * 16 + lr;
      if (colg >= HDIM) continue;
#pragma unroll
      for (int reg = 0; reg < 4; ++reg) {
        int row = m0 + wr * 32 + fi * 16 + lq * 4 + reg;
        float v = acc[fi][fj][reg] + biasp[1536 + colg];
        out[(size_t)row * HDIM + colg] = v > 0.f ? v : 0.f;
      }
    }
}

// ====================== host launcher ======================
extern "C" void kernel_launch(void* const* d_in, const int* in_sizes, int n_in,
                              void* d_out, int out_size, void* d_ws, size_t ws_size,
                              hipStream_t stream) {
  const int* wid = (const int*)d_in[0];
  const int* src = (const int*)d_in[1];
  const int* dst = (const int*)d_in[2];
  const int* sched = (const int*)d_in[4];
  const float* emb = (const float*)d_in[5];
  const float* Wz = (const float*)d_in[6];
  const float* bz = (const float*)d_in[7];
  const float* Wr = (const float*)d_in[8];
  const float* Ur = (const float*)d_in[9];
  const float* bur = (const float*)d_in[10];
  const float* Wh = (const float*)d_in[11];
  const float* bh = (const float*)d_in[12];
  const float* Wg = (const float*)d_in[13];
  const float* bg = (const float*)d_in[14];
  float* out = (float*)d_out;
  float* ws = (float*)d_ws;

  // ---- workspace layout (fp32 units); ~135 MB ----
  size_t o = 0;
  u16* x_p = (u16*)(ws + o);     o += (size_t)NNODES * HP / 2;
  u16* Xzh = (u16*)(ws + o);     o += (size_t)NNODES * 1024 / 2;
  u16* Xr = (u16*)(ws + o);      o += (size_t)NNODES * HP / 2;
  u16* node_m = (u16*)(ws + o);  o += (size_t)NNODES * HP / 2;
  u16* node_rm = (u16*)(ws + o); o += (size_t)NNODES * HP / 2;
  u16* mup = (u16*)(ws + o);     o += (size_t)EUP * HP / 2;
  u16* rmup = (u16*)(ws + o);    o += (size_t)EUP * HP / 2;
  u16* WpreT = (u16*)(ws + o);   o += (size_t)1536 * HP / 2;
  u16* WzbT = (u16*)(ws + o);    o += (size_t)HP * HP / 2;
  u16* WhbT = (u16*)(ws + o);    o += (size_t)HP * HP / 2;
  u16* UrT = (u16*)(ws + o);     o += (size_t)HP * HP / 2;
  u16* WgT = (u16*)(ws + o);     o += (size_t)HP * 1024 / 2;
  float* biasp = ws + o;         o += (size_t)4 * HP;
  if (ws_size < o * sizeof(float)) return;  // diagnostic guard

  // zero node_m + node_rm (contiguous bf16 region)
  size_t zbytes = (size_t)2 * NNODES * HP * 2;
  zero_ws<<<2048, 256, 0, stream>>>((float4*)node_m, (int)(zbytes / 16));

  int prep_elems = 1536 * 512 + 3 * 262144 + 512 * 1024 + 4 * HP;
  prep_pad<<<(prep_elems + 255) / 256, 256, 0, stream>>>(
      Wz, Wh, Wr, Ur, Wg, bz, bh, bur, bg, WpreT, WzbT, WhbT, UrT, WgT, biasp);

  gather_embed<<<(NNODES * 64 + 255) / 256, 256, 0, stream>>>(wid, emb, x_p);

  mfma_pre<<<256 * 24, 256, 0, stream>>>(x_p, WpreT, Xzh, Xr);

  for (int lvl = 0; lvl < NLVL; ++lvl) {
    int L = (lvl < 6) ? (LMAX >> lvl) : (256 << (lvl - 6));
    const int* schedrow = sched + (size_t)lvl * LMAX;
    int mode = (lvl == 0) ? 2 : (lvl < 6 ? 0 : 1);
    fused_level<<<L / 32, 256, 0, stream>>>(
        mode, schedrow, src, dst, node_m, node_rm, mup, rmup,
        Xzh, Xr, WzbT, WhbT, UrT, biasp);
  }

  mfma_final<<<256 * 8, 256, 0, stream>>>(x_p, node_m, WgT, biasp, out);
}

// Round 7
// 557.811 us; speedup vs baseline: 3.3303x; 3.3303x over previous
//
#include <hip/hip_runtime.h>
#include <math.h>

// ---------------- problem constants ----------------
#define NTREES 128
#define NPT 127
#define NNODES (NTREES*NPT)      // 16256
#define EUP (NTREES*(NPT-1))     // 16128
#define HDIM 450
#define HP 512
#define LMAX 8192
#define NLVL 12

typedef unsigned short u16;
typedef __attribute__((ext_vector_type(8))) short bf16x8;
typedef __attribute__((ext_vector_type(4))) float f32x4;

__device__ __forceinline__ float sigmoidf_(float x) { return 1.f / (1.f + expf(-x)); }
__device__ __forceinline__ u16 f2b(float x) {
  unsigned u = __float_as_uint(x);
  return (u16)((u + 0x7FFFu + ((u >> 16) & 1u)) >> 16);
}
__device__ __forceinline__ float b2f(u16 h) { return __uint_as_float(((unsigned)h) << 16); }
// elementwise bf16 difference computed in fp32
__device__ __forceinline__ bf16x8 sub8(bf16x8 a, bf16x8 b) {
  bf16x8 r;
#pragma unroll
  for (int i = 0; i < 8; ++i) r[i] = (short)f2b(b2f((u16)a[i]) - b2f((u16)b[i]));
  return r;
}

// LDS tile: [64 rows][64 bf16] = 128B/row, 8 slots of 16B, XOR-swizzled by row&7
__device__ __forceinline__ u16* ldsp(u16* base, int row, int slot) {
  return base + row * 64 + ((slot ^ (row & 7)) << 3);
}
#define MFMA(a, b, c) __builtin_amdgcn_mfma_f32_16x16x32_bf16(a, b, c, 0, 0, 0)

// XCD-aware (nt, mt) from 1-D bid; all 8 nt-blocks of one mt land on one XCD
// (requires Mt%8==0 for the swizzled path; fallback = legacy dim3(8,Mt) order).
__device__ __forceinline__ void swz_tiles(int bid, int Mt, int& nt, int& mt) {
  if (Mt & 7) { nt = bid & 7; mt = bid >> 3; }
  else { int xcd = bid & 7; int q = bid >> 3; nt = q & 7; mt = (q & ~7) | xcd; }
}

// ============== zero-fill ==============
__global__ void zero_ws(float4* __restrict__ p, int n4) {
  int i = blockIdx.x * 256 + threadIdx.x;
  int stride = gridDim.x * 256;
  for (; i < n4; i += stride) p[i] = make_float4(0.f, 0.f, 0.f, 0.f);
}

// ============== prep: bf16 TRANSPOSED zero-padded weights ==============
__global__ void prep_pad(const float* __restrict__ Wz, const float* __restrict__ Wh,
                         const float* __restrict__ Wr, const float* __restrict__ Ur,
                         const float* __restrict__ Wg,
                         const float* __restrict__ bz, const float* __restrict__ bh,
                         const float* __restrict__ bur, const float* __restrict__ bg,
                         u16* __restrict__ WpreT, u16* __restrict__ WzbT,
                         u16* __restrict__ WhbT, u16* __restrict__ UrT,
                         u16* __restrict__ WgT, float* __restrict__ biasp) {
  int idx = blockIdx.x * 256 + threadIdx.x;
  if (idx < 1536 * 512) {                         // WpreT[n][k]
    int n = idx >> 9, k = idx & 511;
    int sel = n >> 9, j = n & 511;
    float v = 0.f;
    if (k < HDIM && j < HDIM) {
      const float* W = (sel == 0) ? Wz : (sel == 1) ? Wh : Wr;
      v = W[k * HDIM + j];
    }
    WpreT[idx] = f2b(v);
    return;
  }
  idx -= 1536 * 512;
  if (idx < 3 * 262144) {                         // WzbT, WhbT, UrT
    int which = idx >> 18; int r = idx & 262143;
    int n = r >> 9, k = r & 511;
    float v = 0.f;
    if (k < HDIM && n < HDIM)
      v = (which == 0) ? Wz[(HDIM + k) * HDIM + n]
        : (which == 1) ? Wh[(HDIM + k) * HDIM + n]
                       : Ur[k * HDIM + n];
    ((which == 0) ? WzbT : (which == 1) ? WhbT : UrT)[r] = f2b(v);
    return;
  }
  idx -= 3 * 262144;
  if (idx < 512 * 1024) {                         // WgT[n][k], k in [0,1024)
    int n = idx >> 10, k = idx & 1023;
    float v = 0.f;
    if (n < HDIM) {
      if (k < HDIM) v = Wg[k * HDIM + n];
      else if (k >= HP && (k - HP) < HDIM) v = Wg[(HDIM + k - HP) * HDIM + n];
    }
    WgT[idx] = f2b(v);
    return;
  }
  idx -= 512 * 1024;
  if (idx < 4 * HP) {                             // biases fp32
    int which = idx >> 9, j = idx & 511;
    float v = 0.f;
    if (j < HDIM)
      v = ((which == 0) ? bz : (which == 1) ? bh : (which == 2) ? bur : bg)[j];
    biasp[idx] = v;
  }
}

// ============== embedding gather -> bf16 x_p[NNODES][512] ==============
__global__ void gather_embed(const int* __restrict__ wid, const float* __restrict__ emb,
                             u16* __restrict__ xp) {
  int gid = blockIdx.x * 256 + threadIdx.x;
  if (gid >= NNODES * 64) return;
  int row = gid >> 6, g = gid & 63;
  int j0 = g * 8;
  const float* er = emb + (size_t)wid[row] * HDIM;
  float f[8] = {0.f, 0.f, 0.f, 0.f, 0.f, 0.f, 0.f, 0.f};
  if (j0 <= 440) {
#pragma unroll
    for (int q = 0; q < 4; ++q) {
      float2 p = *(const float2*)(er + j0 + q * 2);
      f[q * 2] = p.x; f[q * 2 + 1] = p.y;
    }
  } else if (j0 == 448) {
    f[0] = er[448]; f[1] = er[449];
  }
  bf16x8 v;
#pragma unroll
  for (int q = 0; q < 8; ++q) v[q] = (short)f2b(f[q]);
  *(bf16x8*)(xp + (size_t)row * HP + j0) = v;
}

// ============== MFMA GEMM: Xpre = x @ Wpre -> bf16 Xzh, Xr (XCD-swizzled) ==============
__global__ __launch_bounds__(256, 4) void mfma_pre(
    const u16* __restrict__ xp, const u16* __restrict__ WpreT,
    u16* __restrict__ Xzh, u16* __restrict__ Xr) {
  __shared__ u16 Al[64 * 64], Bl[64 * 64];
  int bid = blockIdx.x;                // grid = 256*24
  int xcd = bid & 7, q0 = bid >> 3;
  int nt = q0 % 24;
  int mt = (q0 / 24) * 8 + xcd;
  if (mt >= NNODES / 64) return;
  int n0 = nt * 64, m0 = mt * 64;
  int tid = threadIdx.x;
  int l = tid & 63, w = tid >> 6, wr = w >> 1, wc = w & 1, lr = l & 15, lq = l >> 4;
  int sr = tid >> 2, skc = tid & 3;
  const u16* abase = xp + (size_t)(m0 + sr) * HP + skc * 16;
  const u16* bbase = WpreT + (size_t)(n0 + sr) * HP + skc * 16;
  f32x4 acc[2][2] = {};
  for (int kt = 0; kt < HP; kt += 64) {
    *(bf16x8*)ldsp(Al, sr, 2 * skc) = ((const bf16x8*)(abase + kt))[0];
    *(bf16x8*)ldsp(Al, sr, 2 * skc + 1) = ((const bf16x8*)(abase + kt))[1];
    *(bf16x8*)ldsp(Bl, sr, 2 * skc) = ((const bf16x8*)(bbase + kt))[0];
    *(bf16x8*)ldsp(Bl, sr, 2 * skc + 1) = ((const bf16x8*)(bbase + kt))[1];
    __syncthreads();
#pragma unroll
    for (int kk = 0; kk < 64; kk += 32) {
      int slot = (kk >> 3) + lq;
      bf16x8 fa0 = *(bf16x8*)ldsp(Al, wr * 32 + lr, slot);
      bf16x8 fa1 = *(bf16x8*)ldsp(Al, wr * 32 + 16 + lr, slot);
      bf16x8 fb0 = *(bf16x8*)ldsp(Bl, wc * 32 + lr, slot);
      bf16x8 fb1 = *(bf16x8*)ldsp(Bl, wc * 32 + 16 + lr, slot);
      acc[0][0] = MFMA(fa0, fb0, acc[0][0]); acc[0][1] = MFMA(fa0, fb1, acc[0][1]);
      acc[1][0] = MFMA(fa1, fb0, acc[1][0]); acc[1][1] = MFMA(fa1, fb1, acc[1][1]);
    }
    __syncthreads();
  }
#pragma unroll
  for (int fi = 0; fi < 2; ++fi)
#pragma unroll
    for (int fj = 0; fj < 2; ++fj) {
      int colg = n0 + wc * 32 + fj * 16 + lr;
#pragma unroll
      for (int reg = 0; reg < 4; ++reg) {
        int row = m0 + wr * 32 + fi * 16 + lq * 4 + reg;
        u16 o = f2b(acc[fi][fj][reg]);
        if (colg < 1024) Xzh[(size_t)row * 1024 + colg] = o;
        else Xr[(size_t)row * HP + (colg - 1024)] = o;
      }
    }
}

// ============== level 0: m_new = sig(Xz+bz)*tanh(Xh+bh) -> bf16 mup ==============
__global__ void leaf_lvl0(const int* __restrict__ sched0, const int* __restrict__ src,
                          const u16* __restrict__ Xzh, const float* __restrict__ biasp,
                          u16* __restrict__ mup) {
  int gid = blockIdx.x * 256 + threadIdx.x;   // 8192 * 128
  int r = gid >> 7, g = gid & 127;
  int e = sched0[r];
  int se = src[e];
  int col = g * 4;
  ushort4 xz = *(const ushort4*)(Xzh + (size_t)se * 1024 + col);
  ushort4 xh = *(const ushort4*)(Xzh + (size_t)se * 1024 + 512 + col);
  float4 bz = *(const float4*)(biasp + col);
  float4 bh = *(const float4*)(biasp + 512 + col);
  ushort4 o;
  o.x = f2b(sigmoidf_(b2f(xz.x) + bz.x) * tanhf(b2f(xh.x) + bh.x));
  o.y = f2b(sigmoidf_(b2f(xz.y) + bz.y) * tanhf(b2f(xh.y) + bh.y));
  o.z = f2b(sigmoidf_(b2f(xz.z) + bz.z) * tanhf(b2f(xh.z) + bh.z));
  o.w = f2b(sigmoidf_(b2f(xz.w) + bz.w) * tanhf(b2f(xh.w) + bh.w));
  *(ushort4*)(mup + (size_t)e * HP + col) = o;
}

// ============== up-level GEMM1 (dual): z/mt/m_new ==============
__global__ __launch_bounds__(256, 4) void mfma_lvl1_up(
    const int* __restrict__ schedrow, const int* __restrict__ src,
    const u16* __restrict__ node_m, const u16* __restrict__ node_rm,
    const u16* __restrict__ Xzh, const u16* __restrict__ WzbT,
    const u16* __restrict__ WhbT, const float* __restrict__ biasp,
    u16* __restrict__ mup) {
  __shared__ u16 Asl[64 * 64], Aal[64 * 64], Bzl[64 * 64], Btl[64 * 64];
  __shared__ int e_s[64], se_s[64];
  int nt, mt;
  swz_tiles(blockIdx.x, gridDim.x >> 3, nt, mt);
  int n0 = nt * 64, m0 = mt * 64;
  int tid = threadIdx.x;
  if (tid < 64) { int e = schedrow[m0 + tid]; e_s[tid] = e; se_s[tid] = src[e]; }
  __syncthreads();
  int l = tid & 63, w = tid >> 6, wr = w >> 1, wc = w & 1, lr = l & 15, lq = l >> 4;
  int sr = tid >> 2, skc = tid & 3;
  int se_st = se_s[sr];
  const u16* pmb = node_m + (size_t)se_st * HP + skc * 16;
  const u16* prb = node_rm + (size_t)se_st * HP + skc * 16;
  const u16* bzb = WzbT + (size_t)(n0 + sr) * HP + skc * 16;
  const u16* btb = WhbT + (size_t)(n0 + sr) * HP + skc * 16;
  f32x4 accZ[2][2] = {}, accT[2][2] = {};
  for (int kt = 0; kt < HP; kt += 64) {
    *(bf16x8*)ldsp(Asl, sr, 2 * skc) = ((const bf16x8*)(pmb + kt))[0];
    *(bf16x8*)ldsp(Asl, sr, 2 * skc + 1) = ((const bf16x8*)(pmb + kt))[1];
    *(bf16x8*)ldsp(Aal, sr, 2 * skc) = ((const bf16x8*)(prb + kt))[0];
    *(bf16x8*)ldsp(Aal, sr, 2 * skc + 1) = ((const bf16x8*)(prb + kt))[1];
    *(bf16x8*)ldsp(Bzl, sr, 2 * skc) = ((const bf16x8*)(bzb + kt))[0];
    *(bf16x8*)ldsp(Bzl, sr, 2 * skc + 1) = ((const bf16x8*)(bzb + kt))[1];
    *(bf16x8*)ldsp(Btl, sr, 2 * skc) = ((const bf16x8*)(btb + kt))[0];
    *(bf16x8*)ldsp(Btl, sr, 2 * skc + 1) = ((const bf16x8*)(btb + kt))[1];
    __syncthreads();
#pragma unroll
    for (int kk = 0; kk < 64; kk += 32) {
      int slot = (kk >> 3) + lq;
      bf16x8 a0 = *(bf16x8*)ldsp(Asl, wr * 32 + lr, slot);
      bf16x8 a1 = *(bf16x8*)ldsp(Asl, wr * 32 + 16 + lr, slot);
      bf16x8 c0 = *(bf16x8*)ldsp(Aal, wr * 32 + lr, slot);
      bf16x8 c1 = *(bf16x8*)ldsp(Aal, wr * 32 + 16 + lr, slot);
      bf16x8 z0 = *(bf16x8*)ldsp(Bzl, wc * 32 + lr, slot);
      bf16x8 z1 = *(bf16x8*)ldsp(Bzl, wc * 32 + 16 + lr, slot);
      bf16x8 t0 = *(bf16x8*)ldsp(Btl, wc * 32 + lr, slot);
      bf16x8 t1 = *(bf16x8*)ldsp(Btl, wc * 32 + 16 + lr, slot);
      accZ[0][0] = MFMA(a0, z0, accZ[0][0]); accZ[0][1] = MFMA(a0, z1, accZ[0][1]);
      accZ[1][0] = MFMA(a1, z0, accZ[1][0]); accZ[1][1] = MFMA(a1, z1, accZ[1][1]);
      accT[0][0] = MFMA(c0, t0, accT[0][0]); accT[0][1] = MFMA(c0, t1, accT[0][1]);
      accT[1][0] = MFMA(c1, t0, accT[1][0]); accT[1][1] = MFMA(c1, t1, accT[1][1]);
    }
    __syncthreads();
  }
#pragma unroll
  for (int fi = 0; fi < 2; ++fi)
#pragma unroll
    for (int fj = 0; fj < 2; ++fj) {
      int colg = n0 + wc * 32 + fj * 16 + lr;
#pragma unroll
      for (int reg = 0; reg < 4; ++reg) {
        int row = wr * 32 + fi * 16 + lq * 4 + reg;
        int e = e_s[row], se = se_s[row];
        float xz = b2f(Xzh[(size_t)se * 1024 + colg]);
        float xh = b2f(Xzh[(size_t)se * 1024 + 512 + colg]);
        float sv = b2f(node_m[(size_t)se * HP + colg]);
        float z = sigmoidf_(accZ[fi][fj][reg] + xz + biasp[colg]);
        float t = tanhf(accT[fi][fj][reg] + xh + biasp[512 + colg]);
        mup[(size_t)e * HP + colg] = f2b((1.f - z) * sv + z * t);
      }
    }
}

// ============== down-level GEMM1 (dual, A = differences) ==============
__global__ __launch_bounds__(256, 4) void mfma_lvl1_down(
    const int* __restrict__ schedrow, const int* __restrict__ src,
    const u16* __restrict__ node_m, const u16* __restrict__ node_rm,
    const u16* __restrict__ mup, const u16* __restrict__ rmup,
    const u16* __restrict__ Xzh, const u16* __restrict__ WzbT,
    const u16* __restrict__ WhbT, const float* __restrict__ biasp,
    u16* __restrict__ dtmp) {
  __shared__ u16 Asl[64 * 64], Aal[64 * 64], Bzl[64 * 64], Btl[64 * 64];
  __shared__ int se_s[64], eu_s[64];
  int nt, mt;
  swz_tiles(blockIdx.x, gridDim.x >> 3, nt, mt);
  int n0 = nt * 64, m0 = mt * 64;
  int tid = threadIdx.x;
  if (tid < 64) { int e = schedrow[m0 + tid]; eu_s[tid] = e - EUP; se_s[tid] = src[e]; }
  __syncthreads();
  int l = tid & 63, w = tid >> 6, wr = w >> 1, wc = w & 1, lr = l & 15, lq = l >> 4;
  int sr = tid >> 2, skc = tid & 3;
  int se_st = se_s[sr], eu_st = eu_s[sr];
  const u16* pmb = node_m + (size_t)se_st * HP + skc * 16;
  const u16* pub = mup + (size_t)eu_st * HP + skc * 16;
  const u16* prb = node_rm + (size_t)se_st * HP + skc * 16;
  const u16* pvb = rmup + (size_t)eu_st * HP + skc * 16;
  const u16* bzb = WzbT + (size_t)(n0 + sr) * HP + skc * 16;
  const u16* btb = WhbT + (size_t)(n0 + sr) * HP + skc * 16;
  f32x4 accZ[2][2] = {}, accT[2][2] = {};
  for (int kt = 0; kt < HP; kt += 64) {
    *(bf16x8*)ldsp(Asl, sr, 2 * skc) = sub8(((const bf16x8*)(pmb + kt))[0], ((const bf16x8*)(pub + kt))[0]);
    *(bf16x8*)ldsp(Asl, sr, 2 * skc + 1) = sub8(((const bf16x8*)(pmb + kt))[1], ((const bf16x8*)(pub + kt))[1]);
    *(bf16x8*)ldsp(Aal, sr, 2 * skc) = sub8(((const bf16x8*)(prb + kt))[0], ((const bf16x8*)(pvb + kt))[0]);
    *(bf16x8*)ldsp(Aal, sr, 2 * skc + 1) = sub8(((const bf16x8*)(prb + kt))[1], ((const bf16x8*)(pvb + kt))[1]);
    *(bf16x8*)ldsp(Bzl, sr, 2 * skc) = ((const bf16x8*)(bzb + kt))[0];
    *(bf16x8*)ldsp(Bzl, sr, 2 * skc + 1) = ((const bf16x8*)(bzb + kt))[1];
    *(bf16x8*)ldsp(Btl, sr, 2 * skc) = ((const bf16x8*)(btb + kt))[0];
    *(bf16x8*)ldsp(Btl, sr, 2 * skc + 1) = ((const bf16x8*)(btb + kt))[1];
    __syncthreads();
#pragma unroll
    for (int kk = 0; kk < 64; kk += 32) {
      int slot = (kk >> 3) + lq;
      bf16x8 a0 = *(bf16x8*)ldsp(Asl, wr * 32 + lr, slot);
      bf16x8 a1 = *(bf16x8*)ldsp(Asl, wr * 32 + 16 + lr, slot);
      bf16x8 c0 = *(bf16x8*)ldsp(Aal, wr * 32 + lr, slot);
      bf16x8 c1 = *(bf16x8*)ldsp(Aal, wr * 32 + 16 + lr, slot);
      bf16x8 z0 = *(bf16x8*)ldsp(Bzl, wc * 32 + lr, slot);
      bf16x8 z1 = *(bf16x8*)ldsp(Bzl, wc * 32 + 16 + lr, slot);
      bf16x8 t0 = *(bf16x8*)ldsp(Btl, wc * 32 + lr, slot);
      bf16x8 t1 = *(bf16x8*)ldsp(Btl, wc * 32 + 16 + lr, slot);
      accZ[0][0] = MFMA(a0, z0, accZ[0][0]); accZ[0][1] = MFMA(a0, z1, accZ[0][1]);
      accZ[1][0] = MFMA(a1, z0, accZ[1][0]); accZ[1][1] = MFMA(a1, z1, accZ[1][1]);
      accT[0][0] = MFMA(c0, t0, accT[0][0]); accT[0][1] = MFMA(c0, t1, accT[0][1]);
      accT[1][0] = MFMA(c1, t0, accT[1][0]); accT[1][1] = MFMA(c1, t1, accT[1][1]);
    }
    __syncthreads();
  }
#pragma unroll
  for (int fi = 0; fi < 2; ++fi)
#pragma unroll
    for (int fj = 0; fj < 2; ++fj) {
      int colg = n0 + wc * 32 + fj * 16 + lr;
#pragma unroll
      for (int reg = 0; reg < 4; ++reg) {
        int row = wr * 32 + fi * 16 + lq * 4 + reg;
        int se = se_s[row], eu = eu_s[row];
        float xz = b2f(Xzh[(size_t)se * 1024 + colg]);
        float xh = b2f(Xzh[(size_t)se * 1024 + 512 + colg]);
        float sv = b2f(node_m[(size_t)se * HP + colg]) - b2f(mup[(size_t)eu * HP + colg]);
        float z = sigmoidf_(accZ[fi][fj][reg] + xz + biasp[colg]);
        float t = tanhf(accT[fi][fj][reg] + xh + biasp[512 + colg]);
        dtmp[(size_t)(m0 + row) * HP + colg] = f2b((1.f - z) * sv + z * t);
      }
    }
}

// ============== up-level GEMM2: r, rmup, pair-store node accumulators ==============
__global__ __launch_bounds__(256, 4) void mfma_lvl2_up(
    const int* __restrict__ schedrow, const int* __restrict__ dst,
    const u16* __restrict__ mup, u16* __restrict__ rmup,
    u16* __restrict__ node_m, u16* __restrict__ node_rm,
    const u16* __restrict__ Xr, const u16* __restrict__ UrT,
    const float* __restrict__ biasp) {
  __shared__ u16 Al[64 * 64], Bl[64 * 64];
  __shared__ int e_s[64], de_s[64];
  int nt, mt;
  swz_tiles(blockIdx.x, gridDim.x >> 3, nt, mt);
  int n0 = nt * 64, m0 = mt * 64;
  int tid = threadIdx.x;
  if (tid < 64) { int e = schedrow[m0 + tid]; e_s[tid] = e; de_s[tid] = dst[e]; }
  __syncthreads();
  int l = tid & 63, w = tid >> 6, wr = w >> 1, wc = w & 1, lr = l & 15, lq = l >> 4;
  int sr = tid >> 2, skc = tid & 3;
  const u16* ab = mup + (size_t)e_s[sr] * HP + skc * 16;
  const u16* bb = UrT + (size_t)(n0 + sr) * HP + skc * 16;
  f32x4 acc[2][2] = {};
  for (int kt = 0; kt < HP; kt += 64) {
    *(bf16x8*)ldsp(Al, sr, 2 * skc) = ((const bf16x8*)(ab + kt))[0];
    *(bf16x8*)ldsp(Al, sr, 2 * skc + 1) = ((const bf16x8*)(ab + kt))[1];
    *(bf16x8*)ldsp(Bl, sr, 2 * skc) = ((const bf16x8*)(bb + kt))[0];
    *(bf16x8*)ldsp(Bl, sr, 2 * skc + 1) = ((const bf16x8*)(bb + kt))[1];
    __syncthreads();
#pragma unroll
    for (int kk = 0; kk < 64; kk += 32) {
      int slot = (kk >> 3) + lq;
      bf16x8 fa0 = *(bf16x8*)ldsp(Al, wr * 32 + lr, slot);
      bf16x8 fa1 = *(bf16x8*)ldsp(Al, wr * 32 + 16 + lr, slot);
      bf16x8 fb0 = *(bf16x8*)ldsp(Bl, wc * 32 + lr, slot);
      bf16x8 fb1 = *(bf16x8*)ldsp(Bl, wc * 32 + 16 + lr, slot);
      acc[0][0] = MFMA(fa0, fb0, acc[0][0]); acc[0][1] = MFMA(fa0, fb1, acc[0][1]);
      acc[1][0] = MFMA(fa1, fb0, acc[1][0]); acc[1][1] = MFMA(fa1, fb1, acc[1][1]);
    }
    __syncthreads();
  }
#pragma unroll
  for (int fi = 0; fi < 2; ++fi)
#pragma unroll
    for (int fj = 0; fj < 2; ++fj) {
      int colg = n0 + wc * 32 + fj * 16 + lr;
      int rowbase = wr * 32 + fi * 16 + lq * 4;
      float mv[4], rmv[4];
#pragma unroll
      for (int reg = 0; reg < 4; ++reg) {
        int row = rowbase + reg;
        int e = e_s[row], de = de_s[row];
        mv[reg] = b2f(mup[(size_t)e * HP + colg]);
        float r = sigmoidf_(acc[fi][fj][reg] + b2f(Xr[(size_t)de * HP + colg]) + biasp[1024 + colg]);
        rmv[reg] = r * mv[reg];
        rmup[(size_t)e * HP + colg] = f2b(rmv[reg]);
      }
      int de0 = de_s[rowbase], de2 = de_s[rowbase + 2];
      node_m[(size_t)de0 * HP + colg] = f2b(mv[0] + mv[1]);
      node_rm[(size_t)de0 * HP + colg] = f2b(rmv[0] + rmv[1]);
      node_m[(size_t)de2 * HP + colg] = f2b(mv[2] + mv[3]);
      node_rm[(size_t)de2 * HP + colg] = f2b(rmv[2] + rmv[3]);
    }
}

// ============== down-level GEMM2: r; node accumulators += ==============
__global__ __launch_bounds__(256, 4) void mfma_lvl2_down(
    const int* __restrict__ schedrow, const int* __restrict__ dst,
    const u16* __restrict__ dtmp,
    u16* __restrict__ node_m, u16* __restrict__ node_rm,
    const u16* __restrict__ Xr, const u16* __restrict__ UrT,
    const float* __restrict__ biasp) {
  __shared__ u16 Al[64 * 64], Bl[64 * 64];
  __shared__ int de_s[64];
  int nt, mt;
  swz_tiles(blockIdx.x, gridDim.x >> 3, nt, mt);
  int n0 = nt * 64, m0 = mt * 64;
  int tid = threadIdx.x;
  if (tid < 64) de_s[tid] = dst[schedrow[m0 + tid]];
  __syncthreads();
  int l = tid & 63, w = tid >> 6, wr = w >> 1, wc = w & 1, lr = l & 15, lq = l >> 4;
  int sr = tid >> 2, skc = tid & 3;
  const u16* ab = dtmp + (size_t)(m0 + sr) * HP + skc * 16;
  const u16* bb = UrT + (size_t)(n0 + sr) * HP + skc * 16;
  f32x4 acc[2][2] = {};
  for (int kt = 0; kt < HP; kt += 64) {
    *(bf16x8*)ldsp(Al, sr, 2 * skc) = ((const bf16x8*)(ab + kt))[0];
    *(bf16x8*)ldsp(Al, sr, 2 * skc + 1) = ((const bf16x8*)(ab + kt))[1];
    *(bf16x8*)ldsp(Bl, sr, 2 * skc) = ((const bf16x8*)(bb + kt))[0];
    *(bf16x8*)ldsp(Bl, sr, 2 * skc + 1) = ((const bf16x8*)(bb + kt))[1];
    __syncthreads();
#pragma unroll
    for (int kk = 0; kk < 64; kk += 32) {
      int slot = (kk >> 3) + lq;
      bf16x8 fa0 = *(bf16x8*)ldsp(Al, wr * 32 + lr, slot);
      bf16x8 fa1 = *(bf16x8*)ldsp(Al, wr * 32 + 16 + lr, slot);
      bf16x8 fb0 = *(bf16x8*)ldsp(Bl, wc * 32 + lr, slot);
      bf16x8 fb1 = *(bf16x8*)ldsp(Bl, wc * 32 + 16 + lr, slot);
      acc[0][0] = MFMA(fa0, fb0, acc[0][0]); acc[0][1] = MFMA(fa0, fb1, acc[0][1]);
      acc[1][0] = MFMA(fa1, fb0, acc[1][0]); acc[1][1] = MFMA(fa1, fb1, acc[1][1]);
    }
    __syncthreads();
  }
#pragma unroll
  for (int fi = 0; fi < 2; ++fi)
#pragma unroll
    for (int fj = 0; fj < 2; ++fj) {
      int colg = n0 + wc * 32 + fj * 16 + lr;
#pragma unroll
      for (int reg = 0; reg < 4; ++reg) {
        int row = wr * 32 + fi * 16 + lq * 4 + reg;
        int de = de_s[row];
        size_t nidx = (size_t)de * HP + colg;
        float mv = b2f(dtmp[(size_t)(m0 + row) * HP + colg]);
        float r = sigmoidf_(acc[fi][fj][reg] + b2f(Xr[nidx]) + biasp[1024 + colg]);
        node_m[nidx] = f2b(b2f(node_m[nidx]) + mv);
        node_rm[nidx] = f2b(b2f(node_rm[nidx]) + r * mv);
      }
    }
}

// ============== final GEMM: h = relu([x, node_m] @ Wg + bg) (XCD-swizzled) ==============
__global__ __launch_bounds__(256, 4) void mfma_final(
    const u16* __restrict__ xp, const u16* __restrict__ node_m,
    const u16* __restrict__ WgT, const float* __restrict__ biasp,
    float* __restrict__ out) {
  __shared__ u16 Al[64 * 64], Bl[64 * 64];
  int bid = blockIdx.x;                // grid = 256*8
  int xcd = bid & 7, q0 = bid >> 3;
  int nt = q0 % 8;
  int mt = (q0 / 8) * 8 + xcd;
  if (mt >= NNODES / 64) return;
  int n0 = nt * 64, m0 = mt * 64;
  int tid = threadIdx.x;
  int l = tid & 63, w = tid >> 6, wr = w >> 1, wc = w & 1, lr = l & 15, lq = l >> 4;
  int sr = tid >> 2, skc = tid & 3;
  const u16* axb = xp + (size_t)(m0 + sr) * HP + skc * 16;
  const u16* anb = node_m + (size_t)(m0 + sr) * HP + skc * 16;
  const u16* bb = WgT + (size_t)(n0 + sr) * 1024 + skc * 16;
  f32x4 acc[2][2] = {};
  for (int kt = 0; kt < 1024; kt += 64) {
    const u16* ap = (kt < HP) ? (axb + kt) : (anb + (kt - HP));
    *(bf16x8*)ldsp(Al, sr, 2 * skc) = ((const bf16x8*)ap)[0];
    *(bf16x8*)ldsp(Al, sr, 2 * skc + 1) = ((const bf16x8*)ap)[1];
    *(bf16x8*)ldsp(Bl, sr, 2 * skc) = ((const bf16x8*)(bb + kt))[0];
    *(bf16x8*)ldsp(Bl, sr, 2 * skc + 1) = ((const bf16x8*)(bb + kt))[1];
    __syncthreads();
#pragma unroll
    for (int kk = 0; kk < 64; kk += 32) {
      int slot = (kk >> 3) + lq;
      bf16x8 fa0 = *(bf16x8*)ldsp(Al, wr * 32 + lr, slot);
      bf16x8 fa1 = *(bf16x8*)ldsp(Al, wr * 32 + 16 + lr, slot);
      bf16x8 fb0 = *(bf16x8*)ldsp(Bl, wc * 32 + lr, slot);
      bf16x8 fb1 = *(bf16x8*)ldsp(Bl, wc * 32 + 16 + lr, slot);
      acc[0][0] = MFMA(fa0, fb0, acc[0][0]); acc[0][1] = MFMA(fa0, fb1, acc[0][1]);
      acc[1][0] = MFMA(fa1, fb0, acc[1][0]); acc[1][1] = MFMA(fa1, fb1, acc[1][1]);
    }
    __syncthreads();
  }
#pragma unroll
  for (int fi = 0; fi < 2; ++fi)
#pragma unroll
    for (int fj = 0; fj < 2; ++fj) {
      int colg = n0 + wc * 32 + fj * 16 + lr;
      if (colg >= HDIM) continue;
#pragma unroll
      for (int reg = 0; reg < 4; ++reg) {
        int row = m0 + wr * 32 + fi * 16 + lq * 4 + reg;
        float v = acc[fi][fj][reg] + biasp[1536 + colg];
        out[(size_t)row * HDIM + colg] = v > 0.f ? v : 0.f;
      }
    }
}

// ====================== host launcher ======================
extern "C" void kernel_launch(void* const* d_in, const int* in_sizes, int n_in,
                              void* d_out, int out_size, void* d_ws, size_t ws_size,
                              hipStream_t stream) {
  const int* wid = (const int*)d_in[0];
  const int* src = (const int*)d_in[1];
  const int* dst = (const int*)d_in[2];
  const int* sched = (const int*)d_in[4];
  const float* emb = (const float*)d_in[5];
  const float* Wz = (const float*)d_in[6];
  const float* bz = (const float*)d_in[7];
  const float* Wr = (const float*)d_in[8];
  const float* Ur = (const float*)d_in[9];
  const float* bur = (const float*)d_in[10];
  const float* Wh = (const float*)d_in[11];
  const float* bh = (const float*)d_in[12];
  const float* Wg = (const float*)d_in[13];
  const float* bg = (const float*)d_in[14];
  float* out = (float*)d_out;
  float* ws = (float*)d_ws;

  // ---- workspace layout (fp32 units); all state bf16, ~150 MB total ----
  size_t o = 0;
  u16* x_p = (u16*)(ws + o);     o += (size_t)NNODES * HP / 2;
  u16* Xzh = (u16*)(ws + o);     o += (size_t)NNODES * 1024 / 2;
  u16* Xr = (u16*)(ws + o);      o += (size_t)NNODES * HP / 2;
  u16* node_m = (u16*)(ws + o);  o += (size_t)NNODES * HP / 2;
  u16* node_rm = (u16*)(ws + o); o += (size_t)NNODES * HP / 2;
  u16* mup = (u16*)(ws + o);     o += (size_t)EUP * HP / 2;
  u16* rmup = (u16*)(ws + o);    o += (size_t)EUP * HP / 2;
  u16* dtmp = (u16*)(ws + o);    o += (size_t)LMAX * HP / 2;
  u16* WpreT = (u16*)(ws + o);   o += (size_t)1536 * HP / 2;
  u16* WzbT = (u16*)(ws + o);    o += (size_t)HP * HP / 2;
  u16* WhbT = (u16*)(ws + o);    o += (size_t)HP * HP / 2;
  u16* UrT = (u16*)(ws + o);     o += (size_t)HP * HP / 2;
  u16* WgT = (u16*)(ws + o);     o += (size_t)HP * 1024 / 2;
  float* biasp = ws + o;         o += (size_t)4 * HP;
  if (ws_size < o * sizeof(float)) return;  // diagnostic guard

  // zero node_m + node_rm (contiguous bf16 region)
  size_t zbytes = (size_t)2 * NNODES * HP * 2;
  zero_ws<<<2048, 256, 0, stream>>>((float4*)node_m, (int)(zbytes / 16));

  int prep_elems = 1536 * 512 + 3 * 262144 + 512 * 1024 + 4 * HP;
  prep_pad<<<(prep_elems + 255) / 256, 256, 0, stream>>>(
      Wz, Wh, Wr, Ur, Wg, bz, bh, bur, bg, WpreT, WzbT, WhbT, UrT, WgT, biasp);

  gather_embed<<<(NNODES * 64 + 255) / 256, 256, 0, stream>>>(wid, emb, x_p);

  mfma_pre<<<256 * 24, 256, 0, stream>>>(x_p, WpreT, Xzh, Xr);

  for (int lvl = 0; lvl < NLVL; ++lvl) {
    int L = (lvl < 6) ? (LMAX >> lvl) : (256 << (lvl - 6));
    const int* schedrow = sched + (size_t)lvl * LMAX;
    if (lvl == 0) {
      leaf_lvl0<<<4096, 256, 0, stream>>>(schedrow, src, Xzh, biasp, mup);
    } else if (lvl < 6) {
      mfma_lvl1_up<<<8 * (L / 64), 256, 0, stream>>>(
          schedrow, src, node_m, node_rm, Xzh, WzbT, WhbT, biasp, mup);
    } else {
      mfma_lvl1_down<<<8 * (L / 64), 256, 0, stream>>>(
          schedrow, src, node_m, node_rm, mup, rmup, Xzh, WzbT, WhbT, biasp, dtmp);
    }
    if (lvl < 6) {
      mfma_lvl2_up<<<8 * (L / 64), 256, 0, stream>>>(
          schedrow, dst, mup, rmup, node_m, node_rm, Xr, UrT, biasp);
    } else {
      mfma_lvl2_down<<<8 * (L / 64), 256, 0, stream>>>(
          schedrow, dst, dtmp, node_m, node_rm, Xr, UrT, biasp);
    }
  }

  mfma_final<<<256 * 8, 256, 0, stream>>>(x_p, node_m, WgT, biasp, out);
}